// Round 11
// baseline (374.913 us; speedup 1.0000x reference)
//
#include <hip/hip_runtime.h>
#include <math.h>

#define NVOX 110592   // 48*48*48

typedef _Float16 f16x8 __attribute__((ext_vector_type(8)));
typedef _Float16 f16x4 __attribute__((ext_vector_type(4)));
typedef _Float16 f16x2 __attribute__((ext_vector_type(2)));
typedef float    f32x4 __attribute__((ext_vector_type(4)));

__device__ __forceinline__ void fmas4(float4& a, const float4& xv, float p) {
    a.x = fmaf(xv.x, p, a.x);
    a.y = fmaf(xv.y, p, a.y);
    a.z = fmaf(xv.z, p, a.z);
    a.w = fmaf(xv.w, p, a.w);
}
__device__ __forceinline__ float comp4(const float4& v, int j) {
    return j == 0 ? v.x : (j == 1 ? v.y : (j == 2 ? v.z : v.w));
}

// XCD-aware bijective swizzle (8 XCDs; grid % 8 == 0). Neighbor (d,h) rows
// share 2/3 of their halo -> keep them on the same XCD's L2/L1.
__device__ __forceinline__ int xcd_swizzle(int bx, int nwg) {
    int chunk = nwg >> 3;
    return (bx & 7) * chunk + (bx >> 3);
}

// ---------------------------------------------------------------------------
// K0: merged prep (unchanged).
// ---------------------------------------------------------------------------
__global__ __launch_bounds__(256) void k_prep(
    const float* __restrict__ feat, const float* __restrict__ x,
    const float* __restrict__ w1, const float* __restrict__ w2,
    _Float16* __restrict__ featT, _Float16* __restrict__ xT,
    _Float16* __restrict__ w1h, _Float16* __restrict__ w2h)
{
    __shared__ _Float16 tile[64 * 36];
    int bx = blockIdx.x;
    int t = threadIdx.x;

    if (bx >= 3456) {                        // weight prep
        int e = (bx - 3456) * 256 + t;
        if (e < 64 * 32 * 27) {
            int oc = e / 864;
            int r = e - oc * 864;
            int ci = r / 27;
            int tap = r - ci * 27;
            w1h[oc * 864 + tap * 32 + ci] = (_Float16)w1[e];
        }
        int e2 = e - 55296;
        if (e2 >= 0 && e2 < 224 * 64) {
            int oc = e2 >> 6, k = e2 & 63;
            w2h[e2] = (oc < 216) ? (_Float16)w2[oc * 64 + k] : (_Float16)0.f;
        }
        return;
    }

    int which = bx >= 1728;
    int v0 = (which ? bx - 1728 : bx) * 64;
    const float* s = which ? x : feat;
    _Float16* dt = which ? xT : featT;

    for (int i = t; i < 1024; i += 256) {
        int c2 = i >> 6, dv = i & 63;
        f16x2 v;
        v.x = (_Float16)s[(2 * c2) * NVOX + v0 + dv];
        v.y = (_Float16)s[(2 * c2 + 1) * NVOX + v0 + dv];
        *(f16x2*)(tile + dv * 36 + c2 * 2) = v;
    }
    __syncthreads();
    for (int i = t; i < 512; i += 256) {
        int dv = i >> 3, ch = i & 7;
        f16x4 v = *(const f16x4*)(tile + dv * 36 + ch * 4);
        *(f16x4*)(dt + (v0 + dv) * 32 + ch * 4) = v;
    }
}

// ---------------------------------------------------------------------------
// K1: fused per (d,h) row, 512 threads.  LDS cut 79 KB -> 49.9 KB:
// feat staging X (36 KB) and mbuf (43 KB) are NEVER live simultaneously
// (X dies at end of B), so mbuf aliases X's tail; phase F reads x DIRECTLY
// from global f16 xT (28.8 KB/block halo fits L1; wave access = 8x64B
// contiguous chunks).  -> 3 blocks/CU, 6 waves/SIMD (was 2 blk, 4 w/SIMD).
//  A: stage featT 3x3 halo -> X [450 col][40 f16]
//  B: conv3x3x3 via MFMA (R3 8-wave structure, measured best)
//  C: bias+SiLU -> hl [48 px][72 f16]  (= smem[0..6912B), X head)
//  D: conv1x1 -> mbuf [8 sub][48 vox][28 f32] at smem+6912B
//  E: softmax(27) in mbuf (384 thr) — no x staging anymore
//  F: 27-tap combine, wi-OUTERMOST (live regs ~45, no spill), p from mbuf,
//     x from global xT, stores = R3's exact clean pattern (WRITE 148 MB).
// ---------------------------------------------------------------------------
__global__ __launch_bounds__(512, 6) void k_main(
    const _Float16* __restrict__ featT, const _Float16* __restrict__ xT,
    const _Float16* __restrict__ w1h, const float* __restrict__ b1,
    const _Float16* __restrict__ w2h, const float* __restrict__ b2,
    float* __restrict__ out)
{
    __shared__ float smem[12480];              // 49,920 B
    _Float16* X  = (_Float16*)smem;            // [450][40] f16 feat staging
    _Float16* hl = (_Float16*)smem;            // [48][72] f16 (aliases X head)
    float* mbuf  = smem + 1728;                // [8][48][28] f32 (after hl)

    int bx = xcd_swizzle(blockIdx.x, gridDim.x);
    int d = bx / 48, hh = bx - d * 48;
    int t = threadIdx.x;

    // ---- phase A: stage featT neighborhood (replicate-clamped)
    for (int i = t; i < 1800; i += 512) {
        int col = i >> 2, chunk = i & 3;        // col = dzdy*50 + px
        int dzdy = col / 50;
        int px = col - dzdy * 50;
        int dz = dzdy / 3, dy = dzdy - dz * 3;
        int zz = min(max(d + dz - 1, 0), 47);
        int yy = min(max(hh + dy - 1, 0), 47);
        int xx = min(max(px - 1, 0), 47);
        int vox = (zz * 48 + yy) * 48 + xx;
        *(f16x8*)(X + col * 40 + chunk * 8) =
            *(const f16x8*)(featT + vox * 32 + chunk * 8);
    }
    __syncthreads();

    int wid = t >> 6;                           // 0..7
    int lane = t & 63;
    int mcol = lane & 15;
    int q = lane >> 4;
    int ocs = wid & 3;                          // oc strip for conv1

    // ---- phase B: conv1 MFMA (R3). waves 0-3: px {0,2}; waves 4-7: {1}
    f32x4 c1a = {0.f, 0.f, 0.f, 0.f};
    f32x4 c1b = {0.f, 0.f, 0.f, 0.f};
    {
        const _Float16* wbase = w1h + (ocs * 16 + mcol) * 864 + q * 8;
#pragma unroll 3
        for (int dzdy = 0; dzdy < 9; ++dzdy) {
            const _Float16* brow = X + (dzdy * 50 + mcol) * 40 + q * 8;
            const _Float16* wrow = wbase + dzdy * 96;
#pragma unroll
            for (int dx = 0; dx < 3; ++dx) {
                f16x8 av = *(const f16x8*)(wrow + dx * 32);
                const _Float16* bb = brow + dx * 40;
                if (wid < 4) {
                    f16x8 b0 = *(const f16x8*)(bb);
                    f16x8 b2v = *(const f16x8*)(bb + 32 * 40);
                    c1a = __builtin_amdgcn_mfma_f32_16x16x32_f16(av, b0, c1a, 0, 0, 0);
                    c1b = __builtin_amdgcn_mfma_f32_16x16x32_f16(av, b2v, c1b, 0, 0, 0);
                } else {
                    f16x8 b1v = *(const f16x8*)(bb + 16 * 40);
                    c1a = __builtin_amdgcn_mfma_f32_16x16x32_f16(av, b1v, c1a, 0, 0, 0);
                }
            }
        }
    }
    __syncthreads();                            // all X reads done

    // ---- phase C: bias + SiLU -> hl (X head; X tail now dead)
    {
        float4 bv = ((const float4*)b1)[ocs * 4 + q];
        int pxb0 = (wid < 4) ? 0 : 1;
        int px0 = pxb0 * 16 + mcol;
        f16x4 o; float s;
        s = c1a[0] + bv.x; o.x = (_Float16)(s / (1.f + __expf(-s)));
        s = c1a[1] + bv.y; o.y = (_Float16)(s / (1.f + __expf(-s)));
        s = c1a[2] + bv.z; o.z = (_Float16)(s / (1.f + __expf(-s)));
        s = c1a[3] + bv.w; o.w = (_Float16)(s / (1.f + __expf(-s)));
        *(f16x4*)(hl + px0 * 72 + ocs * 16 + q * 4) = o;
        if (wid < 4) {
            int px1 = 32 + mcol;
            s = c1b[0] + bv.x; o.x = (_Float16)(s / (1.f + __expf(-s)));
            s = c1b[1] + bv.y; o.y = (_Float16)(s / (1.f + __expf(-s)));
            s = c1b[2] + bv.z; o.z = (_Float16)(s / (1.f + __expf(-s)));
            s = c1b[3] + bv.w; o.w = (_Float16)(s / (1.f + __expf(-s)));
            *(f16x4*)(hl + px1 * 72 + ocs * 16 + q * 4) = o;
        }
    }
    __syncthreads();                            // hl complete

    // ---- phase D: conv2 MFMA, 42 tiles (14 mt x 3 nt) over 8 waves
    for (int tt = wid; tt < 42; tt += 8) {
        int mt = tt / 3, nt = tt - mt * 3;
        float bias[4];
#pragma unroll
        for (int rr = 0; rr < 4; ++rr) {
            int oc = mt * 16 + q * 4 + rr;
            bias[rr] = (oc < 216) ? b2[oc] : 0.f;
        }
        f32x4 acc = {bias[0], bias[1], bias[2], bias[3]};
#pragma unroll
        for (int ks = 0; ks < 2; ++ks) {
            f16x8 av = *(const f16x8*)(w2h + (mt * 16 + mcol) * 64 + ks * 32 + q * 8);
            f16x8 bv = *(const f16x8*)(hl + (nt * 16 + mcol) * 72 + ks * 32 + q * 8);
            acc = __builtin_amdgcn_mfma_f32_16x16x32_f16(av, bv, acc, 0, 0, 0);
        }
        int vox = nt * 16 + mcol;
#pragma unroll
        for (int rr = 0; rr < 4; ++rr) {
            int oc = mt * 16 + q * 4 + rr;
            if (oc < 216) {
                int sub = oc / 27;
                int n = oc - sub * 27;
                mbuf[(sub * 48 + vox) * 28 + n] = acc[rr];
            }
        }
    }
    __syncthreads();                            // mbuf complete

    // ---- phase E: softmax over 27 taps (8 sub x 48 vox rows)
    if (t < 384) {
        int sub = t / 48;
        int vox = t - sub * 48;
        float4* p4p = (float4*)(mbuf + (sub * 48 + vox) * 28);
        float4 v[7];
#pragma unroll
        for (int g = 0; g < 7; ++g) v[g] = p4p[g];
        float mx = fmaxf(fmaxf(v[6].x, v[6].y), v[6].z);
#pragma unroll
        for (int g = 0; g < 6; ++g)
            mx = fmaxf(mx, fmaxf(fmaxf(v[g].x, v[g].y), fmaxf(v[g].z, v[g].w)));
        float s = 0.f;
#pragma unroll
        for (int g = 0; g < 7; ++g) {
            v[g].x = __expf(v[g].x - mx);
            v[g].y = __expf(v[g].y - mx);
            v[g].z = __expf(v[g].z - mx);
            v[g].w = __expf(v[g].w - mx);
        }
        v[6].w = 0.f;                           // tap 27 pad
#pragma unroll
        for (int g = 0; g < 7; ++g) s += v[g].x + v[g].y + v[g].z + v[g].w;
        float inv = 1.f / s;
#pragma unroll
        for (int g = 0; g < 7; ++g) {
            v[g].x *= inv; v[g].y *= inv; v[g].z *= inv; v[g].w *= inv;
            p4p[g] = v[g];
        }
    }
    __syncthreads();

    // ---- phase F: wi-OUTERMOST; p from mbuf, x from GLOBAL xT (f16).
    // u = t&255, half = t>>8; tx = u&7, cq = (u>>3)&7, sp = u>>6.
    // out[c][2d+i][2h+j][2w+k] = sum_n p[sub][w][n]*x[c][nb(w,n)]
    {
        const float4* m4 = (const float4*)mbuf;
        int u = t & 255;
        int half = t >> 8;
        int w0 = half * 24;
        int tx = u & 7, ty = u >> 3;
        int cq = ty & 7, sp = ty >> 3;          // sp -> (i,j)

        int rb[9];
#pragma unroll
        for (int r = 0; r < 9; ++r) {
            int dz = r / 3, dy = r - (r / 3) * 3;
            int zz = min(max(d + dz - 1, 0), 47);
            int yy = min(max(hh + dy - 1, 0), 47);
            rb[r] = (zz * 48 + yy) * 48;
        }
        int i_ = sp >> 1, j_ = sp & 1;
        int rowz = 2 * d + i_;
        int rowy = 2 * hh + j_;

#pragma unroll
        for (int wi = 0; wi < 3; ++wi) {
            int w_ = w0 + tx + wi * 8;
            int xm = max(w_ - 1, 0), xp = min(w_ + 1, 47);
            float4 a0 = make_float4(0.f, 0.f, 0.f, 0.f);
            float4 a1 = make_float4(0.f, 0.f, 0.f, 0.f);
#pragma unroll
            for (int g = 0; g < 7; ++g) {
                float4 p0 = m4[((sp * 2 + 0) * 48 + w_) * 7 + g];
                float4 p1 = m4[((sp * 2 + 1) * 48 + w_) * 7 + g];
#pragma unroll
                for (int j = 0; j < 4; ++j) {
                    int n = g * 4 + j;
                    if (n < 27) {
                        int r = n / 3;          // compile-time
                        int dx = n - r * 3;
                        int xx = (dx == 0) ? xm : ((dx == 1) ? w_ : xp);
                        f16x4 xr = *(const f16x4*)(xT +
                                      (size_t)(rb[r] + xx) * 32 + cq * 4);
                        float4 xv = make_float4((float)xr.x, (float)xr.y,
                                                (float)xr.z, (float)xr.w);
                        fmas4(a0, xv, comp4(p0, j));
                        fmas4(a1, xv, comp4(p1, j));
                    }
                }
            }
#pragma unroll
            for (int cc = 0; cc < 4; ++cc) {
                int c = cq * 4 + cc;
                float2 v;
                v.x = comp4(a0, cc);            // k = 0
                v.y = comp4(a1, cc);            // k = 1
                *(float2*)(out + (((size_t)c * 96 + rowz) * 96 + rowy) * 96 + 2 * w_) = v;
            }
        }
    }
}

extern "C" void kernel_launch(void* const* d_in, const int* in_sizes, int n_in,
                              void* d_out, int out_size, void* d_ws, size_t ws_size,
                              hipStream_t stream) {
    const float* x    = (const float*)d_in[0];
    const float* feat = (const float*)d_in[1];
    const float* w1   = (const float*)d_in[2];
    const float* b1   = (const float*)d_in[3];
    const float* w2   = (const float*)d_in[4];
    const float* b2   = (const float*)d_in[5];
    float* out = (float*)d_out;

    _Float16* w1h   = (_Float16*)d_ws;                       //    110,592 B
    _Float16* w2h   = (_Float16*)((char*)d_ws + 110592);     //     28,672 B
    _Float16* featT = (_Float16*)((char*)d_ws + 139264);     //  7,077,888 B
    _Float16* xT    = (_Float16*)((char*)d_ws + 7217152);    //  7,077,888 B

    k_prep<<<3728, 256, 0, stream>>>(feat, x, w1, w2, featT, xT, w1h, w2h);
    k_main<<<2304, 512, 0, stream>>>(featT, xT, w1h, b1, w2h, b2, out);
}

// Round 12
// 262.063 us; speedup vs baseline: 1.4306x; 1.4306x over previous
//
#include <hip/hip_runtime.h>
#include <math.h>

#define NVOX 110592   // 48*48*48

typedef _Float16 f16x8 __attribute__((ext_vector_type(8)));
typedef _Float16 f16x4 __attribute__((ext_vector_type(4)));
typedef _Float16 f16x2 __attribute__((ext_vector_type(2)));
typedef float    f32x4 __attribute__((ext_vector_type(4)));

__device__ __forceinline__ void fmas4(float4& a, const float4& xv, float p) {
    a.x = fmaf(xv.x, p, a.x);
    a.y = fmaf(xv.y, p, a.y);
    a.z = fmaf(xv.z, p, a.z);
    a.w = fmaf(xv.w, p, a.w);
}
__device__ __forceinline__ float comp4(const float4& v, int j) {
    return j == 0 ? v.x : (j == 1 ? v.y : (j == 2 ? v.z : v.w));
}

// XCD-aware bijective swizzle (8 XCDs; grid % 8 == 0).
__device__ __forceinline__ int xcd_swizzle(int bx, int nwg) {
    int chunk = nwg >> 3;
    return (bx & 7) * chunk + (bx >> 3);
}

// ---------------------------------------------------------------------------
// K0: merged prep (unchanged, measured ~12 us).
// ---------------------------------------------------------------------------
__global__ __launch_bounds__(256) void k_prep(
    const float* __restrict__ feat, const float* __restrict__ x,
    const float* __restrict__ w1, const float* __restrict__ w2,
    _Float16* __restrict__ featT, _Float16* __restrict__ xT,
    _Float16* __restrict__ w1h, _Float16* __restrict__ w2h)
{
    __shared__ _Float16 tile[64 * 36];
    int bx = blockIdx.x;
    int t = threadIdx.x;

    if (bx >= 3456) {                        // weight prep
        int e = (bx - 3456) * 256 + t;
        if (e < 64 * 32 * 27) {
            int oc = e / 864;
            int r = e - oc * 864;
            int ci = r / 27;
            int tap = r - ci * 27;
            w1h[oc * 864 + tap * 32 + ci] = (_Float16)w1[e];
        }
        int e2 = e - 55296;
        if (e2 >= 0 && e2 < 224 * 64) {
            int oc = e2 >> 6, k = e2 & 63;
            w2h[e2] = (oc < 216) ? (_Float16)w2[oc * 64 + k] : (_Float16)0.f;
        }
        return;
    }

    int which = bx >= 1728;
    int v0 = (which ? bx - 1728 : bx) * 64;
    const float* s = which ? x : feat;
    _Float16* dt = which ? xT : featT;

    for (int i = t; i < 1024; i += 256) {
        int c2 = i >> 6, dv = i & 63;
        f16x2 v;
        v.x = (_Float16)s[(2 * c2) * NVOX + v0 + dv];
        v.y = (_Float16)s[(2 * c2 + 1) * NVOX + v0 + dv];
        *(f16x2*)(tile + dv * 36 + c2 * 2) = v;
    }
    __syncthreads();
    for (int i = t; i < 512; i += 256) {
        int dv = i >> 3, ch = i & 7;
        f16x4 v = *(const f16x4*)(tile + dv * 36 + ch * 4);
        *(f16x4*)(dt + (v0 + dv) * 32 + ch * 4) = v;
    }
}

// ---------------------------------------------------------------------------
// K1: fused per (d,h) row, 512 threads.  = Round-3 kernel (the measured best:
// 130 us, FETCH 28.7, WRITE 148) with LDS cut 79 KB -> 53,904 B by
// TIME-MULTIPLEXED layout -> 3 blocks/CU (was 2), launch_bounds UNCHANGED
// (512,4) so regalloc keeps the proven 64 VGPR (R11's forced-40 spill bug).
//
// LDS timeline (one 53,904 B arena):
//   A/B:  X feat staging [450][40] f16              @ [0, 36864)
//   C/D:  hl [48][72] f16 @ [0,6912) ; mbuf f32 [384][28] @ [6912, 49920)
//   E1:   softmax reads mbuf -> REGISTERS           (then barrier)
//   E2:   pbuf f16 [384][28] @ [0,21504)  +  x stage [450][36] f16
//         @ [21504, 53904)   (all over dead hl/mbuf)
//   F:    R3-F mapping; p from pbuf (f16x4 broadcast reads, bank-clean),
//         x from stride-36 LDS (same 4-way pattern as stride 40).
// ---------------------------------------------------------------------------
__global__ __launch_bounds__(512, 4) void k_main(
    const _Float16* __restrict__ featT, const _Float16* __restrict__ xT,
    const _Float16* __restrict__ w1h, const float* __restrict__ b1,
    const _Float16* __restrict__ w2h, const float* __restrict__ b2,
    float* __restrict__ out)
{
    __shared__ float smem[13476];              // 53,904 B
    _Float16* X  = (_Float16*)smem;            // [450][40] f16 (A/B)
    _Float16* hl = (_Float16*)smem;            // [48][72] f16 (C/D, X head)
    float* mbuf  = smem + 1728;                // [384][28] f32 (D/E1)
    _Float16* pb = (_Float16*)smem;            // [384][28] f16 (E2/F)
    _Float16* xs = (_Float16*)smem + 10752;    // [450][36] f16 (E2/F)

    int bx = xcd_swizzle(blockIdx.x, gridDim.x);
    int d = bx / 48, hh = bx - d * 48;
    int t = threadIdx.x;

    // ---- phase A: stage featT neighborhood (replicate-clamped)
    for (int i = t; i < 1800; i += 512) {
        int col = i >> 2, chunk = i & 3;        // col = dzdy*50 + px
        int dzdy = col / 50;
        int px = col - dzdy * 50;
        int dz = dzdy / 3, dy = dzdy - dz * 3;
        int zz = min(max(d + dz - 1, 0), 47);
        int yy = min(max(hh + dy - 1, 0), 47);
        int xx = min(max(px - 1, 0), 47);
        int vox = (zz * 48 + yy) * 48 + xx;
        *(f16x8*)(X + col * 40 + chunk * 8) =
            *(const f16x8*)(featT + vox * 32 + chunk * 8);
    }
    __syncthreads();

    int wid = t >> 6;                           // 0..7
    int lane = t & 63;
    int mcol = lane & 15;
    int q = lane >> 4;
    int ocs = wid & 3;                          // oc strip for conv1

    // ---- phase B: conv1 MFMA (R3 8-wave). waves 0-3: px {0,2}; 4-7: {1}
    f32x4 c1a = {0.f, 0.f, 0.f, 0.f};
    f32x4 c1b = {0.f, 0.f, 0.f, 0.f};
    {
        const _Float16* wbase = w1h + (ocs * 16 + mcol) * 864 + q * 8;
#pragma unroll 3
        for (int dzdy = 0; dzdy < 9; ++dzdy) {
            const _Float16* brow = X + (dzdy * 50 + mcol) * 40 + q * 8;
            const _Float16* wrow = wbase + dzdy * 96;
#pragma unroll
            for (int dx = 0; dx < 3; ++dx) {
                f16x8 av = *(const f16x8*)(wrow + dx * 32);
                const _Float16* bb = brow + dx * 40;
                if (wid < 4) {
                    f16x8 b0 = *(const f16x8*)(bb);
                    f16x8 b2v = *(const f16x8*)(bb + 32 * 40);
                    c1a = __builtin_amdgcn_mfma_f32_16x16x32_f16(av, b0, c1a, 0, 0, 0);
                    c1b = __builtin_amdgcn_mfma_f32_16x16x32_f16(av, b2v, c1b, 0, 0, 0);
                } else {
                    f16x8 b1v = *(const f16x8*)(bb + 16 * 40);
                    c1a = __builtin_amdgcn_mfma_f32_16x16x32_f16(av, b1v, c1a, 0, 0, 0);
                }
            }
        }
    }
    __syncthreads();                            // all X reads done

    // ---- phase C: bias + SiLU -> hl (X head; X dead)
    {
        float4 bv = ((const float4*)b1)[ocs * 4 + q];
        int pxb0 = (wid < 4) ? 0 : 1;
        int px0 = pxb0 * 16 + mcol;
        f16x4 o; float s;
        s = c1a[0] + bv.x; o.x = (_Float16)(s / (1.f + __expf(-s)));
        s = c1a[1] + bv.y; o.y = (_Float16)(s / (1.f + __expf(-s)));
        s = c1a[2] + bv.z; o.z = (_Float16)(s / (1.f + __expf(-s)));
        s = c1a[3] + bv.w; o.w = (_Float16)(s / (1.f + __expf(-s)));
        *(f16x4*)(hl + px0 * 72 + ocs * 16 + q * 4) = o;
        if (wid < 4) {
            int px1 = 32 + mcol;
            s = c1b[0] + bv.x; o.x = (_Float16)(s / (1.f + __expf(-s)));
            s = c1b[1] + bv.y; o.y = (_Float16)(s / (1.f + __expf(-s)));
            s = c1b[2] + bv.z; o.z = (_Float16)(s / (1.f + __expf(-s)));
            s = c1b[3] + bv.w; o.w = (_Float16)(s / (1.f + __expf(-s)));
            *(f16x4*)(hl + px1 * 72 + ocs * 16 + q * 4) = o;
        }
    }
    __syncthreads();                            // hl complete

    // ---- phase D: conv2 MFMA, 42 tiles (14 mt x 3 nt) over 8 waves
    for (int tt = wid; tt < 42; tt += 8) {
        int mt = tt / 3, nt = tt - mt * 3;
        float bias[4];
#pragma unroll
        for (int rr = 0; rr < 4; ++rr) {
            int oc = mt * 16 + q * 4 + rr;
            bias[rr] = (oc < 216) ? b2[oc] : 0.f;
        }
        f32x4 acc = {bias[0], bias[1], bias[2], bias[3]};
#pragma unroll
        for (int ks = 0; ks < 2; ++ks) {
            f16x8 av = *(const f16x8*)(w2h + (mt * 16 + mcol) * 64 + ks * 32 + q * 8);
            f16x8 bv = *(const f16x8*)(hl + (nt * 16 + mcol) * 72 + ks * 32 + q * 8);
            acc = __builtin_amdgcn_mfma_f32_16x16x32_f16(av, bv, acc, 0, 0, 0);
        }
        int vox = nt * 16 + mcol;
#pragma unroll
        for (int rr = 0; rr < 4; ++rr) {
            int oc = mt * 16 + q * 4 + rr;
            if (oc < 216) {
                int sub = oc / 27;
                int n = oc - sub * 27;
                mbuf[(sub * 48 + vox) * 28 + n] = acc[rr];
            }
        }
    }
    __syncthreads();                            // mbuf complete, hl dead

    // ---- phase E1: softmax in REGISTERS (8 sub x 48 vox rows)
    float4 v[7];
    if (t < 384) {
        const float4* p4p = (const float4*)(mbuf + t * 28);
#pragma unroll
        for (int g = 0; g < 7; ++g) v[g] = p4p[g];
        float mx = fmaxf(fmaxf(v[6].x, v[6].y), v[6].z);
#pragma unroll
        for (int g = 0; g < 6; ++g)
            mx = fmaxf(mx, fmaxf(fmaxf(v[g].x, v[g].y), fmaxf(v[g].z, v[g].w)));
        float s = 0.f;
#pragma unroll
        for (int g = 0; g < 7; ++g) {
            v[g].x = __expf(v[g].x - mx);
            v[g].y = __expf(v[g].y - mx);
            v[g].z = __expf(v[g].z - mx);
            v[g].w = __expf(v[g].w - mx);
        }
        v[6].w = 0.f;                           // tap 27 pad
#pragma unroll
        for (int g = 0; g < 7; ++g) s += v[g].x + v[g].y + v[g].z + v[g].w;
        float inv = 1.f / s;
#pragma unroll
        for (int g = 0; g < 7; ++g) {
            v[g].x *= inv; v[g].y *= inv; v[g].z *= inv; v[g].w *= inv;
        }
    }
    __syncthreads();                            // ALL mbuf f32 reads done

    // ---- phase E2: write p as f16 -> pbuf ; stage xT halo -> xs (stride 36)
    if (t < 384) {
#pragma unroll
        for (int g = 0; g < 7; ++g) {
            f16x4 pv;
            pv.x = (_Float16)v[g].x; pv.y = (_Float16)v[g].y;
            pv.z = (_Float16)v[g].z; pv.w = (_Float16)v[g].w;
            *(f16x4*)(pb + t * 28 + g * 4) = pv;
        }
    }
    for (int i = t; i < 1800; i += 512) {
        int col = i >> 2, chunk = i & 3;        // col = dzdy*50 + px
        int dzdy = col / 50;
        int px = col - dzdy * 50;
        int dz = dzdy / 3, dy = dzdy - dz * 3;
        int zz = min(max(d + dz - 1, 0), 47);
        int yy = min(max(hh + dy - 1, 0), 47);
        int xx = min(max(px - 1, 0), 47);
        int vox = (zz * 48 + yy) * 48 + xx;
        *(f16x8*)(xs + col * 36 + chunk * 8) =
            *(const f16x8*)(xT + vox * 32 + chunk * 8);
    }
    __syncthreads();

    // ---- phase F (R3 mapping): u=t&255, half=t>>8, w0=half*24;
    // tx = u&7, cq = (u>>3)&7, sp = u>>6.  p from pbuf f16 (broadcast reads),
    // x from xs stride 36.  Stores = R3's exact clean pattern.
    {
        int u = t & 255;
        int half = t >> 8;
        int w0 = half * 24;
        int tx = u & 7, ty = u >> 3;
        int cq = ty & 7, sp = ty >> 3;          // sp -> (i,j)
        float4 acc[2][3];
#pragma unroll
        for (int s = 0; s < 2; ++s)
#pragma unroll
            for (int wi = 0; wi < 3; ++wi)
                acc[s][wi] = make_float4(0.f, 0.f, 0.f, 0.f);

#pragma unroll
        for (int g = 0; g < 7; ++g) {
            float4 p4[2][3];
#pragma unroll
            for (int s = 0; s < 2; ++s)
#pragma unroll
                for (int wi = 0; wi < 3; ++wi) {
                    f16x4 pr = *(const f16x4*)(pb +
                        ((sp * 2 + s) * 48 + w0 + tx + wi * 8) * 28 + g * 4);
                    p4[s][wi] = make_float4((float)pr.x, (float)pr.y,
                                            (float)pr.z, (float)pr.w);
                }
#pragma unroll
            for (int j = 0; j < 4; ++j) {
                int n = g * 4 + j;
                if (n < 27) {
                    int dz = n / 9;
                    int rem = n - dz * 9;
                    int dy = rem / 3, dx = rem - dy * 3;
#pragma unroll
                    for (int wi = 0; wi < 3; ++wi) {
                        int col = (dz * 3 + dy) * 50 + w0 + tx + wi * 8 + dx;
                        f16x4 xr = *(const f16x4*)(xs + col * 36 + cq * 4);
                        float4 xv = make_float4((float)xr.x, (float)xr.y,
                                                (float)xr.z, (float)xr.w);
                        fmas4(acc[0][wi], xv, comp4(p4[0][wi], j));
                        fmas4(acc[1][wi], xv, comp4(p4[1][wi], j));
                    }
                }
            }
        }

        int i_ = sp >> 1, j_ = sp & 1;
        int rowz = 2 * d + i_;
        int rowy = 2 * hh + j_;
#pragma unroll
        for (int wi = 0; wi < 3; ++wi) {
            int wg = w0 + tx + wi * 8;
#pragma unroll
            for (int cc = 0; cc < 4; ++cc) {
                int c = cq * 4 + cc;
                float2 vv;
                vv.x = comp4(acc[0][wi], cc);   // k = 0
                vv.y = comp4(acc[1][wi], cc);   // k = 1
                *(float2*)(out + (((size_t)c * 96 + rowz) * 96 + rowy) * 96 + 2 * wg) = vv;
            }
        }
    }
}

extern "C" void kernel_launch(void* const* d_in, const int* in_sizes, int n_in,
                              void* d_out, int out_size, void* d_ws, size_t ws_size,
                              hipStream_t stream) {
    const float* x    = (const float*)d_in[0];
    const float* feat = (const float*)d_in[1];
    const float* w1   = (const float*)d_in[2];
    const float* b1   = (const float*)d_in[3];
    const float* w2   = (const float*)d_in[4];
    const float* b2   = (const float*)d_in[5];
    float* out = (float*)d_out;

    _Float16* w1h   = (_Float16*)d_ws;                       //    110,592 B
    _Float16* w2h   = (_Float16*)((char*)d_ws + 110592);     //     28,672 B
    _Float16* featT = (_Float16*)((char*)d_ws + 139264);     //  7,077,888 B
    _Float16* xT    = (_Float16*)((char*)d_ws + 7217152);    //  7,077,888 B

    k_prep<<<3728, 256, 0, stream>>>(feat, x, w1, w2, featT, xT, w1h, w2h);
    k_main<<<2304, 512, 0, stream>>>(featT, xT, w1h, b1, w2h, b2, out);
}